// Round 4
// baseline (244.885 us; speedup 1.0000x reference)
//
#include <hip/hip_runtime.h>
#include <float.h>
#include <limits.h>
#include <stdint.h>

constexpr int N = 16384;
constexpr int K = 8192;
constexpr int D = 256;

typedef _Float16 half8_t __attribute__((ext_vector_type(8)));
typedef float float4_t __attribute__((ext_vector_type(4)));
typedef float float16_t __attribute__((ext_vector_type(16)));

// ---------------- fallback helper: row sum-of-squares ----------------
__global__ void vq_rowsq(const float* __restrict__ A, float* __restrict__ out) {
    int row = blockIdx.x;
    int lane = threadIdx.x;  // 64
    float4 v = ((const float4*)(A + (size_t)row * D))[lane];
    float s = v.x * v.x + v.y * v.y + v.z * v.z + v.w * v.w;
    #pragma unroll
    for (int o = 32; o > 0; o >>= 1) s += __shfl_down(s, o);
    if (lane == 0) out[row] = s;
}

// =======================================================================
// FAST PATH (R13): 32x32x16 f16 MFMA, E LDS-resident (-2-prescaled),
// X streamed from global. acc initialized to esq so the MFMA chain
// produces the screen score directly (sc = eq + sum(-2e*x)); the ctile
// epilogue is pure cmp/select. Wave tile 64 rows x 64 codes.
// =======================================================================
// Lane-linear tiled layouts (zero bank conflicts, verified R5/R6/R9):
//   Xh[rt*4096 + ds*512 + g*64 + q*16 + r15] chunks (g=localrow>>4)
//   Eh[(ct*8+ds)*512 + (lc>>4)*64 + q*16 + (lc&15)] chunks (lc=code&127)
// chunk = 16B (8 halves) = 8 consecutive dims of one row. For 32x32x16
// fragments, lane l needs (row l&31, k-octet l>>5) -> chunk offset
// alane = ((l>>4)&1)*64 + (l>>5)*16 + (l&15) within a 32-row block.
// Eh stores -2*E (exact power-of-2 scale; esq kept true).

__global__ void vq_prep(const float* __restrict__ X, const float* __restrict__ E,
                        _Float16* __restrict__ Xh, _Float16* __restrict__ Eh,
                        float* __restrict__ esq) {
    int c = blockIdx.x * 256 + threadIdx.x;
    const int XCH = N * 32;  // X chunks; % 256 == 0 so blocks don't mix X/E
    if (c < XCH) {
        int row = c >> 5, q8 = c & 31;
        int ds = q8 >> 2, q = q8 & 3;
        int rt = row >> 7, lr = row & 127;
        int slot = ((lr >> 4) << 6) + (q << 4) + (lr & 15);
        size_t dst = ((size_t)rt * 4096 + ds * 512 + slot) * 8;
        const float4* s4 = (const float4*)(X + (size_t)row * D + q8 * 8);
        float4 v0 = s4[0], v1 = s4[1];
        float x[8] = {v0.x, v0.y, v0.z, v0.w, v1.x, v1.y, v1.z, v1.w};
        half8_t hh;
        #pragma unroll
        for (int i = 0; i < 8; i++) hh[i] = (_Float16)x[i];
        *(half8_t*)(Xh + dst) = hh;
    } else {
        int cc = c - XCH;
        int code = cc >> 5, q8 = cc & 31;
        int ds = q8 >> 2, q = q8 & 3;
        int ct = code >> 7, lc = code & 127;
        int slot = ((lc >> 4) << 6) + (q << 4) + (lc & 15);
        size_t dst = ((size_t)(ct * 8 + ds) * 512 + slot) * 8;
        const float4* s4 = (const float4*)(E + (size_t)code * D + q8 * 8);
        float4 v0 = s4[0], v1 = s4[1];
        float x[8] = {v0.x, v0.y, v0.z, v0.w, v1.x, v1.y, v1.z, v1.w};
        half8_t hh;
        float sq = 0.f;
        #pragma unroll
        for (int i = 0; i < 8; i++) {
            sq += x[i] * x[i];
            hh[i] = (_Float16)(-2.0f * x[i]);  // exact 2^1 scale of (f16)x
        }
        *(half8_t*)(Eh + dst) = hh;
        #pragma unroll
        for (int o = 16; o > 0; o >>= 1) sq += __shfl_xor(sq, o);
        if ((threadIdx.x & 31) == 0) esq[code] = sq;
    }
}

__device__ __forceinline__ void ldg_lds16(const _Float16* g, _Float16* l) {
    __builtin_amdgcn_global_load_lds(
        (const __attribute__((address_space(1))) unsigned int*)g,
        (__attribute__((address_space(3))) unsigned int*)l, 16, 0, 0);
}

constexpr int CS = 8;               // code split; block owns K/CS = 1024 codes
constexpr int KT = (K / 128) / CS;  // 8 128-code ctiles per block

// block: 512 thr = 8 waves = 4 row-groups x 2 code-halves. Block tile
// 256 rows x 128 codes per ctile. Wave tile 64x64: acc[2][2] f32x16
// (128 AGPR). E ctile (128 codes, 64 KB) double-buffered in LDS via
// global_load_lds; X streamed from global (L2-resident, chunk layout).
// Barrier-free inner ds loop; 1 barrier per ctile.
__global__ __launch_bounds__(512, 2) void vq_mfma(
    const _Float16* __restrict__ Xh, const _Float16* __restrict__ Eh,
    const float* __restrict__ esq, float4* __restrict__ pcand) {
    __shared__ _Float16 lds[65536];  // 2 bufs x 4096 chunks x 16B = 128 KB

    const int t = threadIdx.x, w = t >> 6, lane = t & 63;
    const int rs = blockIdx.x;  // row slice 0..63 (256 rows each)
    const int cs = blockIdx.y;  // code split 0..7
    const int c31 = lane & 31, hi = lane >> 5;
    const int alane = ((lane >> 4) & 1) * 64 + hi * 16 + (lane & 15);
    const int wr = w >> 1, wc = w & 1;

    float best[32];
    int bidx[32];
    #pragma unroll
    for (int i = 0; i < 32; i++) { best[i] = FLT_MAX; bidx[i] = 0; }

    // X chunks (global): wave rows = rs*256 + wr*64
    const half8_t* Xg = (const half8_t*)Xh +
        ((size_t)(rs * 2 + (wr >> 1)) * 4096 + (wr & 1) * 256 + alane);
    const half8_t* Eg = (const half8_t*)Eh + (size_t)(cs * KT) * 4096;

    // stage ctile ct into LDS buffer b (linear lane-order copy)
    auto stage = [&](int ct, int b) {
        const half8_t* src = Eg + ((size_t)ct * 4096 + w * 512 + lane);
        _Float16* dst = lds + ((size_t)b * 4096 + w * 512) * 8;
        #pragma unroll
        for (int i = 0; i < 8; i++)
            ldg_lds16((const _Float16*)(src + i * 64), dst + i * 512);
    };

    float16_t acc[2][2];
    float eqc[2], eqn[2];

    stage(0, 0);
    {
        const int code0 = cs * KT * 128 + wc * 64 + c31;
        eqc[0] = esq[code0];
        eqc[1] = esq[code0 + 32];
    }
    __syncthreads();  // buf0 ready

    for (int ct = 0; ct < KT; ct++) {
        if (ct + 1 < KT) stage(ct + 1, (ct + 1) & 1);  // prefetch next ctile

        // init acc = esq: MFMA chain then yields sc = eq + sum(-2e*x)
        #pragma unroll
        for (int mt = 0; mt < 2; mt++)
            #pragma unroll
            for (int nt = 0; nt < 2; nt++)
                #pragma unroll
                for (int r = 0; r < 16; r++) acc[mt][nt][r] = eqc[nt];

        if (ct + 1 < KT) {  // prefetch next ctile's esq
            const int code1 = (cs * KT + ct + 1) * 128 + wc * 64 + c31;
            eqn[0] = esq[code1];
            eqn[1] = esq[code1 + 32];
        }

        const half8_t* Cc = (const half8_t*)lds + (size_t)((ct & 1) * 4096);

        #pragma unroll
        for (int ds = 0; ds < 8; ds++) {
            half8_t Xf[2][2], Ef[2][2];
            #pragma unroll
            for (int mt = 0; mt < 2; mt++)
                #pragma unroll
                for (int ko = 0; ko < 2; ko++)
                    Xf[mt][ko] = Xg[ds * 512 + mt * 128 + ko * 32];
            #pragma unroll
            for (int nt = 0; nt < 2; nt++)
                #pragma unroll
                for (int ko = 0; ko < 2; ko++)
                    Ef[nt][ko] =
                        Cc[ds * 512 + wc * 256 + nt * 128 + ko * 32 + alane];

            __builtin_amdgcn_s_setprio(1);
            #pragma unroll
            for (int ko = 0; ko < 2; ko++)
                #pragma unroll
                for (int mt = 0; mt < 2; mt++)
                    #pragma unroll
                    for (int nt = 0; nt < 2; nt++)
                        acc[mt][nt] = __builtin_amdgcn_mfma_f32_32x32x16_f16(
                            Xf[mt][ko], Ef[nt][ko], acc[mt][nt], 0, 0, 0);
            __builtin_amdgcn_s_setprio(0);
        }

        // ctile epilogue: pure min-update (scores complete in acc)
        const int code0 = (cs * KT + ct) * 128 + wc * 64 + c31;
        #pragma unroll
        for (int nt = 0; nt < 2; nt++) {
            const int code = code0 + nt * 32;
            #pragma unroll
            for (int mt = 0; mt < 2; mt++)
                #pragma unroll
                for (int r = 0; r < 16; r++) {
                    float sc = acc[mt][nt][r];
                    int sl = mt * 16 + r;
                    if (sc < best[sl]) { best[sl] = sc; bidx[sl] = code; }
                }
        }
        eqc[0] = eqn[0];
        eqc[1] = eqn[1];

        __syncthreads();  // all waves done reading buf[ct&1]; next staged
    }

    // per-row top-2 over 64 contributors (wc x c31); LDS reused
    float* smin = (float*)lds;      // [64][256] = 64 KB
    int* sidx = (int*)lds + 16384;  // [64][256] = 64 KB
    const int cont = wc * 32 + c31;
    #pragma unroll
    for (int sl = 0; sl < 32; sl++) {
        int mt = sl >> 4, r = sl & 15;
        int row = wr * 64 + mt * 32 + (r & 3) + 8 * (r >> 2) + 4 * hi;
        smin[cont * 256 + row] = best[sl];
        sidx[cont * 256 + row] = bidx[sl];
    }
    __syncthreads();
    if (t < 256) {
        float m1 = FLT_MAX, m2 = FLT_MAX;
        int i1 = 0, i2 = 0;
        for (int c = 0; c < 64; c++) {
            float v = smin[c * 256 + t];
            int id = sidx[c * 256 + t];
            if (v < m1 || (v == m1 && id < i1)) {
                m2 = m1; i2 = i1; m1 = v; i1 = id;
            } else if (v < m2 || (v == m2 && id < i2)) {
                m2 = v; i2 = id;
            }
        }
        uint32_t pk = ((uint32_t)i1 << 13) | (uint32_t)(i2 & 8191);
        float4 out;
        out.x = m1; out.y = m2; out.z = __int_as_float((int)pk); out.w = 0.f;
        pcand[(size_t)(rs * 256 + t) * CS + cs] = out;
    }
}

__device__ __forceinline__ float wave_sum(float v) {
    #pragma unroll
    for (int o = 1; o < 64; o <<= 1) v += __shfl_xor(v, o);
    return v;
}

// margin-gated final. Screen err bound per score ~0.14 (10-sigma); EB=0.4.
// gap > EB: screen winner provably exact. Else: exact-fp32 rescore of only
// candidates with screened score <= gm1 + EB.
__global__ void vq_rescore(const float* __restrict__ X, const float* __restrict__ E,
                           const float4* __restrict__ pcand, float* __restrict__ out_q,
                           float* __restrict__ out_idx) {
    constexpr float EB = 0.4f;
    int row = blockIdx.x * 4 + (threadIdx.x >> 6);
    int lane = threadIdx.x & 63;

    int cand[2 * CS];
    float csc[2 * CS];
    float gm1 = FLT_MAX, gm2 = FLT_MAX;
    int gi1 = INT_MAX;
    #pragma unroll
    for (int s = 0; s < CS; s++) {
        float4 p = pcand[(size_t)row * CS + s];
        uint32_t pk = (uint32_t)__float_as_int(p.z);
        int i1 = (int)(pk >> 13), i2 = (int)(pk & 8191);
        cand[2 * s] = i1;
        csc[2 * s] = p.x;
        cand[2 * s + 1] = i2;
        csc[2 * s + 1] = p.y;
        if (p.x < gm1 || (p.x == gm1 && i1 < gi1)) {
            gm2 = gm1; gm1 = p.x; gi1 = i1;
        } else if (p.x < gm2) gm2 = p.x;
        if (p.y < gm2) gm2 = p.y;
    }

    int besti = gi1;
    if (gm2 - gm1 <= EB) {  // ambiguous: exact fp32 rescore of survivors
        float4 xv = ((const float4*)(X + (size_t)row * D))[lane];
        float xs = wave_sum(xv.x * xv.x + xv.y * xv.y + xv.z * xv.z + xv.w * xv.w);
        float bestv = FLT_MAX;
        besti = INT_MAX;
        for (int c = 0; c < 2 * CS; c++) {
            if (csc[c] > gm1 + EB) continue;  // cannot be the true winner
            int idx = cand[c];
            float4 e = ((const float4*)(E + (size_t)idx * D))[lane];
            float dp = wave_sum(xv.x * e.x + xv.y * e.y + xv.z * e.z + xv.w * e.w);
            float eq = wave_sum(e.x * e.x + e.y * e.y + e.z * e.z + e.w * e.w);
            float sc = (xs + eq) - 2.f * dp;
            if (sc < bestv || (sc == bestv && idx < besti)) { bestv = sc; besti = idx; }
        }
    }
    if (lane == 0) out_idx[row] = (float)besti;
    float4 bv = ((const float4*)(E + (size_t)besti * D))[lane];
    ((float4*)(out_q + (size_t)row * D))[lane] = bv;
}

// =======================================================================
// FALLBACK (proven R1 fp32 path) — used only if ws_size is too small
// =======================================================================
constexpr int BM = 128, BN = 128, DK = 32, KSPLIT = 8;
constexpr int KCHUNK = K / KSPLIT;
constexpr int LDX = BM + 4, LDE = BN + 4;

__global__ __launch_bounds__(256) void vq_main(
    const float* __restrict__ X, const float* __restrict__ E,
    const float* __restrict__ xsq, const float* __restrict__ esq,
    float* __restrict__ pmin, int* __restrict__ pidx) {
    __shared__ float sx[DK * LDX];
    __shared__ float se[DK * LDE];
    const int t = threadIdx.x;
    const int row0 = blockIdx.x * BM;
    const int kbeg = blockIdx.y * KCHUNK;
    const int lane = t & 63, wave = t >> 6;
    const int lm = lane >> 3, ln = lane & 7;
    const int mf = (wave >> 1) * 64 + lm * 8;
    const int nf = (wave & 1) * 64 + ln * 8;
    float xs[8];
    #pragma unroll
    for (int i = 0; i < 8; i++) xs[i] = xsq[row0 + mf + i];
    float rmin[8];
    int ridx[8];
    #pragma unroll
    for (int i = 0; i < 8; i++) { rmin[i] = FLT_MAX; ridx[i] = 0; }
    const int sm = t >> 3;
    const int sd = (t & 7) * 4;
    for (int kt = kbeg; kt < kbeg + KCHUNK; kt += BN) {
        float acc[8][8];
        #pragma unroll
        for (int i = 0; i < 8; i++)
            #pragma unroll
            for (int j = 0; j < 8; j++) acc[i][j] = 0.0f;
        for (int d0 = 0; d0 < D; d0 += DK) {
            __syncthreads();
            #pragma unroll
            for (int r = 0; r < 4; r++) {
                int row = sm + 32 * r;
                float4 v = *(const float4*)(X + (size_t)(row0 + row) * D + d0 + sd);
                sx[(sd + 0) * LDX + row] = v.x;
                sx[(sd + 1) * LDX + row] = v.y;
                sx[(sd + 2) * LDX + row] = v.z;
                sx[(sd + 3) * LDX + row] = v.w;
                float4 ww = *(const float4*)(E + (size_t)(kt + row) * D + d0 + sd);
                se[(sd + 0) * LDE + row] = ww.x;
                se[(sd + 1) * LDE + row] = ww.y;
                se[(sd + 2) * LDE + row] = ww.z;
                se[(sd + 3) * LDE + row] = ww.w;
            }
            __syncthreads();
            #pragma unroll
            for (int d = 0; d < DK; d++) {
                float4 a0 = *(const float4*)(sx + d * LDX + mf);
                float4 a1 = *(const float4*)(sx + d * LDX + mf + 4);
                float4 b0 = *(const float4*)(se + d * LDE + nf);
                float4 b1 = *(const float4*)(se + d * LDE + nf + 4);
                float a[8] = {a0.x, a0.y, a0.z, a0.w, a1.x, a1.y, a1.z, a1.w};
                float b[8] = {b0.x, b0.y, b0.z, b0.w, b1.x, b1.y, b1.z, b1.w};
                #pragma unroll
                for (int i = 0; i < 8; i++)
                    #pragma unroll
                    for (int j = 0; j < 8; j++) acc[i][j] += a[i] * b[j];
            }
        }
        float es[8];
        #pragma unroll
        for (int j = 0; j < 8; j++) es[j] = esq[kt + nf + j];
        #pragma unroll
        for (int i = 0; i < 8; i++)
            #pragma unroll
            for (int j = 0; j < 8; j++) {
                float s = (xs[i] + es[j]) - 2.0f * acc[i][j];
                if (s < rmin[i]) { rmin[i] = s; ridx[i] = kt + nf + j; }
            }
    }
    __syncthreads();
    float* redm = sx;
    int* redi = (int*)se;
    const int c = (wave & 1) * 8 + ln;
    #pragma unroll
    for (int i = 0; i < 8; i++) {
        int r = (wave >> 1) * 64 + lm * 8 + i;
        redm[r * 16 + c] = rmin[i];
        redi[r * 16 + c] = ridx[i];
    }
    __syncthreads();
    if (t < BM) {
        float bst = redm[t * 16];
        int bi = redi[t * 16];
        #pragma unroll
        for (int c2 = 1; c2 < 16; c2++) {
            float v = redm[t * 16 + c2];
            int id = redi[t * 16 + c2];
            if (v < bst || (v == bst && id < bi)) { bst = v; bi = id; }
        }
        pmin[(size_t)(row0 + t) * KSPLIT + blockIdx.y] = bst;
        pidx[(size_t)(row0 + t) * KSPLIT + blockIdx.y] = bi;
    }
}

__global__ void vq_final(const float* __restrict__ E, const float* __restrict__ pmin,
                         const int* __restrict__ pidx, float* __restrict__ out_q,
                         float* __restrict__ out_idx) {
    int row = blockIdx.x;
    int lane = threadIdx.x;
    float bst = pmin[(size_t)row * KSPLIT];
    int bi = pidx[(size_t)row * KSPLIT];
    #pragma unroll
    for (int s = 1; s < KSPLIT; s++) {
        float v = pmin[(size_t)row * KSPLIT + s];
        int id = pidx[(size_t)row * KSPLIT + s];
        if (v < bst || (v == bst && id < bi)) { bst = v; bi = id; }
    }
    if (lane == 0) out_idx[row] = (float)bi;
    float4 v = ((const float4*)(E + (size_t)bi * D))[lane];
    ((float4*)(out_q + (size_t)row * D))[lane] = v;
}

// =======================================================================
extern "C" void kernel_launch(void* const* d_in, const int* in_sizes, int n_in,
                              void* d_out, int out_size, void* d_ws, size_t ws_size,
                              hipStream_t stream) {
    const float* X = (const float*)d_in[0];  // [N, D]
    const float* E = (const float*)d_in[1];  // [K, D]
    float* out_q = (float*)d_out;
    float* out_idx = (float*)d_out + (size_t)N * D;

    // fast-path ws: Xh(8M) Eh(4M) esq(32K) pcand(N*CS*16 = 2M) ~= 14.3MB
    const size_t need = (size_t)12 * 1024 * 1024 + 32768 + (size_t)N * CS * 16;
    if (ws_size >= need) {
        _Float16* Xh = (_Float16*)d_ws;
        _Float16* Eh = Xh + (size_t)N * D;
        float* esq = (float*)(Eh + (size_t)K * D);
        float4* pcand = (float4*)(esq + K);

        vq_prep<<<(N + K) * 32 / 256, 256, 0, stream>>>(X, E, Xh, Eh, esq);
        dim3 grid(N / 256, CS);
        vq_mfma<<<grid, 512, 0, stream>>>(Xh, Eh, esq, pcand);
        vq_rescore<<<N / 4, 256, 0, stream>>>(X, E, pcand, out_q, out_idx);
    } else {
        float* esq = (float*)d_ws;
        float* xsq = esq + K;
        float* pmin = xsq + N;
        int* pidx = (int*)(pmin + (size_t)N * KSPLIT);
        vq_rowsq<<<K, 64, 0, stream>>>(E, esq);
        vq_rowsq<<<N, 64, 0, stream>>>(X, xsq);
        dim3 grid(N / BM, KSPLIT);
        vq_main<<<grid, 256, 0, stream>>>(X, E, xsq, esq, pmin, pidx);
        vq_final<<<N, 64, 0, stream>>>(E, pmin, pidx, out_q, out_idx);
    }
}

// Round 5
// 200.223 us; speedup vs baseline: 1.2231x; 1.2231x over previous
//
#include <hip/hip_runtime.h>
#include <float.h>
#include <limits.h>
#include <stdint.h>

constexpr int N = 16384;
constexpr int K = 8192;
constexpr int D = 256;

typedef _Float16 half8_t __attribute__((ext_vector_type(8)));
typedef float float4_t __attribute__((ext_vector_type(4)));

// ---------------- fallback helper: row sum-of-squares ----------------
__global__ void vq_rowsq(const float* __restrict__ A, float* __restrict__ out) {
    int row = blockIdx.x;
    int lane = threadIdx.x;  // 64
    float4 v = ((const float4*)(A + (size_t)row * D))[lane];
    float s = v.x * v.x + v.y * v.y + v.z * v.z + v.w * v.w;
    #pragma unroll
    for (int o = 32; o > 0; o >>= 1) s += __shfl_down(s, o);
    if (lane == 0) out[row] = s;
}

// =======================================================================
// FAST PATH (R14): R3 structure (E LDS-resident dbuf, X streamed,
// 16x16x32 MFMA) + two deltas:
//   1) 1024-thr block = 16 waves, wave tile 32 rows x 128 codes ->
//      4 waves/SIMD at IDENTICAL per-CU traffic (R3 was 2 waves/SIMD
//      in lockstep; the finer split covers ds_read->MFMA latency and
//      the epilogue VALU phase). Register budget checked: acc 64 +
//      best/bidx 16 + eq 8 + Xf 8 + Ef 16 (nt-quads) + addr ~12 = ~124
//      <= 128-reg cap for 16 waves/CU.
//   2) Eh pre-scaled by -2 (exact), acc initialized to esq -> MFMA
//      chain emits the screen score directly; epilogue is pure
//      cmp/select (validated numerically in R4; its failure was spills).
// =======================================================================
// Lane-linear tiled layouts (zero bank conflicts, verified R5/R6/R9):
//   Xh[rt*4096 + ds*512 + g*64 + q*16 + r15] chunks (g=localrow>>4)
//   Eh[(ct*8+ds)*512 + (lc>>4)*64 + q*16 + (lc&15)] chunks (lc=code&127)
// chunk = 16B (8 halves); q = dim-quad within the 32-dim step ds.
// Eh stores -2*E (exact power-of-2 scale; esq kept true).

__global__ void vq_prep(const float* __restrict__ X, const float* __restrict__ E,
                        _Float16* __restrict__ Xh, _Float16* __restrict__ Eh,
                        float* __restrict__ esq) {
    int c = blockIdx.x * 256 + threadIdx.x;
    const int XCH = N * 32;  // X chunks; % 256 == 0 so blocks don't mix X/E
    if (c < XCH) {
        int row = c >> 5, q8 = c & 31;
        int ds = q8 >> 2, q = q8 & 3;
        int rt = row >> 7, lr = row & 127;
        int slot = ((lr >> 4) << 6) + (q << 4) + (lr & 15);
        size_t dst = ((size_t)rt * 4096 + ds * 512 + slot) * 8;
        const float4* s4 = (const float4*)(X + (size_t)row * D + q8 * 8);
        float4 v0 = s4[0], v1 = s4[1];
        float x[8] = {v0.x, v0.y, v0.z, v0.w, v1.x, v1.y, v1.z, v1.w};
        half8_t hh;
        #pragma unroll
        for (int i = 0; i < 8; i++) hh[i] = (_Float16)x[i];
        *(half8_t*)(Xh + dst) = hh;
    } else {
        int cc = c - XCH;
        int code = cc >> 5, q8 = cc & 31;
        int ds = q8 >> 2, q = q8 & 3;
        int ct = code >> 7, lc = code & 127;
        int slot = ((lc >> 4) << 6) + (q << 4) + (lc & 15);
        size_t dst = ((size_t)(ct * 8 + ds) * 512 + slot) * 8;
        const float4* s4 = (const float4*)(E + (size_t)code * D + q8 * 8);
        float4 v0 = s4[0], v1 = s4[1];
        float x[8] = {v0.x, v0.y, v0.z, v0.w, v1.x, v1.y, v1.z, v1.w};
        half8_t hh;
        float sq = 0.f;
        #pragma unroll
        for (int i = 0; i < 8; i++) {
            sq += x[i] * x[i];
            hh[i] = (_Float16)(-2.0f * x[i]);  // exact 2^1 scale of (f16)x
        }
        *(half8_t*)(Eh + dst) = hh;
        #pragma unroll
        for (int o = 16; o > 0; o >>= 1) sq += __shfl_xor(sq, o);
        if ((threadIdx.x & 31) == 0) esq[code] = sq;
    }
}

__device__ __forceinline__ void ldg_lds16(const _Float16* g, _Float16* l) {
    __builtin_amdgcn_global_load_lds(
        (const __attribute__((address_space(1))) unsigned int*)g,
        (__attribute__((address_space(3))) unsigned int*)l, 16, 0, 0);
}

constexpr int CS = 8;               // code split; block owns K/CS = 1024 codes
constexpr int KT = (K / 128) / CS;  // 8 128-code ctiles per block

// block: 1024 thr = 16 waves. Wave w owns rows [rs*512 + w*32, +32), tile
// 32 rows x 128 codes (acc[2][8] = 64 regs). E ctile (128 codes x 256d =
// 64 KB) staged to LDS via global_load_lds, double-buffered (128 KB);
// all 16 waves share it. X streamed from global (L2-resident chunks).
// 1 block/CU, 4 waves/SIMD. Barrier-free inner ds loop; 1 barrier/ctile.
__global__ __launch_bounds__(1024, 4) void vq_mfma(
    const _Float16* __restrict__ Xh, const _Float16* __restrict__ Eh,
    const float* __restrict__ esq, float4* __restrict__ pcand) {
    __shared__ _Float16 lds[65536];  // 2 bufs x 4096 chunks x 16B = 128 KB

    const int t = threadIdx.x, w = t >> 6, lane = t & 63;
    const int rs = blockIdx.x;  // row slice 0..31 (512 rows each)
    const int cs = blockIdx.y;  // code split 0..7
    const int c15 = lane & 15, quad = lane >> 4;

    float best[8];
    int bidx[8];
    #pragma unroll
    for (int i = 0; i < 8; i++) { best[i] = FLT_MAX; bidx[i] = 0; }

    // X chunks (global): wave rows = rs*512 + w*32
    //   rt = rs*4 + (w>>2); within rtile g0 = (w&3)*2 -> chunk offs (w&3)*128
    const half8_t* Xg = (const half8_t*)Xh +
        ((size_t)(rs * 4 + (w >> 2)) * 4096 + (w & 3) * 128 + lane);
    const half8_t* Eg = (const half8_t*)Eh + (size_t)(cs * KT) * 4096;

    // stage ctile ct into LDS buffer b (linear lane-order copy; wave w
    // does chunks [w*256, w*256+256): 4 x global_load_lds 16B per lane)
    auto stage = [&](int ct, int b) {
        const half8_t* src = Eg + ((size_t)ct * 4096 + w * 256 + lane);
        _Float16* dst = lds + ((size_t)b * 4096 + w * 256) * 8;
        #pragma unroll
        for (int i = 0; i < 4; i++)
            ldg_lds16((const _Float16*)(src + i * 64), dst + i * 512);
    };

    float4_t acc[2][8];
    float eq[8];

    stage(0, 0);
    __syncthreads();  // buf0 ready

    for (int ct = 0; ct < KT; ct++) {
        if (ct + 1 < KT) stage(ct + 1, (ct + 1) & 1);  // prefetch next ctile

        const int code0 = (cs * KT + ct) * 128;
        #pragma unroll
        for (int nt = 0; nt < 8; nt++) eq[nt] = esq[code0 + nt * 16 + c15];

        // init acc = esq: MFMA chain then yields sc = eq + sum(-2e*x)
        #pragma unroll
        for (int mt = 0; mt < 2; mt++)
            #pragma unroll
            for (int nt = 0; nt < 8; nt++)
                #pragma unroll
                for (int r = 0; r < 4; r++) acc[mt][nt][r] = eq[nt];

        const half8_t* Cc = (const half8_t*)lds + (size_t)((ct & 1) * 4096);

        #pragma unroll
        for (int ds = 0; ds < 8; ds++) {
            half8_t Xf[2];
            Xf[0] = Xg[ds * 512];
            Xf[1] = Xg[ds * 512 + 64];

            half8_t Ef[4];
            #pragma unroll
            for (int nt = 0; nt < 4; nt++) Ef[nt] = Cc[ds * 512 + nt * 64 + lane];
            __builtin_amdgcn_s_setprio(1);
            #pragma unroll
            for (int mt = 0; mt < 2; mt++)
                #pragma unroll
                for (int nt = 0; nt < 4; nt++)
                    acc[mt][nt] = __builtin_amdgcn_mfma_f32_16x16x32_f16(
                        Xf[mt], Ef[nt], acc[mt][nt], 0, 0, 0);
            __builtin_amdgcn_s_setprio(0);

            #pragma unroll
            for (int nt = 0; nt < 4; nt++)
                Ef[nt] = Cc[ds * 512 + (nt + 4) * 64 + lane];
            __builtin_amdgcn_s_setprio(1);
            #pragma unroll
            for (int mt = 0; mt < 2; mt++)
                #pragma unroll
                for (int nt = 0; nt < 4; nt++)
                    acc[mt][nt + 4] = __builtin_amdgcn_mfma_f32_16x16x32_f16(
                        Xf[mt], Ef[nt], acc[mt][nt + 4], 0, 0, 0);
            __builtin_amdgcn_s_setprio(0);
        }

        // ctile epilogue: pure min-update (scores complete in acc)
        #pragma unroll
        for (int nt = 0; nt < 8; nt++) {
            const int code = code0 + nt * 16 + c15;
            #pragma unroll
            for (int mt = 0; mt < 2; mt++)
                #pragma unroll
                for (int rg = 0; rg < 4; rg++) {
                    float sc = acc[mt][nt][rg];
                    int sl = mt * 4 + rg;
                    if (sc < best[sl]) { best[sl] = sc; bidx[sl] = code; }
                }
        }

        __syncthreads();  // all waves done reading buf[ct&1]; next staged
    }

    // per-row top-2 over 16 contributors (c15 lanes); LDS reused
    float* smin = (float*)lds;          // [16][512] = 32 KB
    int* sidx = (int*)lds + 8192;       // [16][512] = 32 KB
    #pragma unroll
    for (int sl = 0; sl < 8; sl++) {
        int row = w * 32 + (sl >> 2) * 16 + quad * 4 + (sl & 3);
        smin[c15 * 512 + row] = best[sl];
        sidx[c15 * 512 + row] = bidx[sl];
    }
    __syncthreads();
    if (t < 512) {
        float m1 = FLT_MAX, m2 = FLT_MAX;
        int i1 = 0, i2 = 0;
        for (int c = 0; c < 16; c++) {
            float v = smin[c * 512 + t];
            int id = sidx[c * 512 + t];
            if (v < m1 || (v == m1 && id < i1)) {
                m2 = m1; i2 = i1; m1 = v; i1 = id;
            } else if (v < m2 || (v == m2 && id < i2)) {
                m2 = v; i2 = id;
            }
        }
        uint32_t pk = ((uint32_t)i1 << 13) | (uint32_t)(i2 & 8191);
        float4 out;
        out.x = m1; out.y = m2; out.z = __int_as_float((int)pk); out.w = 0.f;
        pcand[(size_t)(rs * 512 + t) * CS + cs] = out;
    }
}

__device__ __forceinline__ float wave_sum(float v) {
    #pragma unroll
    for (int o = 1; o < 64; o <<= 1) v += __shfl_xor(v, o);
    return v;
}

// margin-gated final. Screen err bound per score ~0.14 (10-sigma); EB=0.4.
// gap > EB: screen winner provably exact. Else: exact-fp32 rescore of only
// candidates with screened score <= gm1 + EB.
__global__ void vq_rescore(const float* __restrict__ X, const float* __restrict__ E,
                           const float4* __restrict__ pcand, float* __restrict__ out_q,
                           float* __restrict__ out_idx) {
    constexpr float EB = 0.4f;
    int row = blockIdx.x * 4 + (threadIdx.x >> 6);
    int lane = threadIdx.x & 63;

    int cand[2 * CS];
    float csc[2 * CS];
    float gm1 = FLT_MAX, gm2 = FLT_MAX;
    int gi1 = INT_MAX;
    #pragma unroll
    for (int s = 0; s < CS; s++) {
        float4 p = pcand[(size_t)row * CS + s];
        uint32_t pk = (uint32_t)__float_as_int(p.z);
        int i1 = (int)(pk >> 13), i2 = (int)(pk & 8191);
        cand[2 * s] = i1;
        csc[2 * s] = p.x;
        cand[2 * s + 1] = i2;
        csc[2 * s + 1] = p.y;
        if (p.x < gm1 || (p.x == gm1 && i1 < gi1)) {
            gm2 = gm1; gm1 = p.x; gi1 = i1;
        } else if (p.x < gm2) gm2 = p.x;
        if (p.y < gm2) gm2 = p.y;
    }

    int besti = gi1;
    if (gm2 - gm1 <= EB) {  // ambiguous: exact fp32 rescore of survivors
        float4 xv = ((const float4*)(X + (size_t)row * D))[lane];
        float xs = wave_sum(xv.x * xv.x + xv.y * xv.y + xv.z * xv.z + xv.w * xv.w);
        float bestv = FLT_MAX;
        besti = INT_MAX;
        for (int c = 0; c < 2 * CS; c++) {
            if (csc[c] > gm1 + EB) continue;  // cannot be the true winner
            int idx = cand[c];
            float4 e = ((const float4*)(E + (size_t)idx * D))[lane];
            float dp = wave_sum(xv.x * e.x + xv.y * e.y + xv.z * e.z + xv.w * e.w);
            float eq = wave_sum(e.x * e.x + e.y * e.y + e.z * e.z + e.w * e.w);
            float sc = (xs + eq) - 2.f * dp;
            if (sc < bestv || (sc == bestv && idx < besti)) { bestv = sc; besti = idx; }
        }
    }
    if (lane == 0) out_idx[row] = (float)besti;
    float4 bv = ((const float4*)(E + (size_t)besti * D))[lane];
    ((float4*)(out_q + (size_t)row * D))[lane] = bv;
}

// =======================================================================
// FALLBACK (proven R1 fp32 path) — used only if ws_size is too small
// =======================================================================
constexpr int BM = 128, BN = 128, DK = 32, KSPLIT = 8;
constexpr int KCHUNK = K / KSPLIT;
constexpr int LDX = BM + 4, LDE = BN + 4;

__global__ __launch_bounds__(256) void vq_main(
    const float* __restrict__ X, const float* __restrict__ E,
    const float* __restrict__ xsq, const float* __restrict__ esq,
    float* __restrict__ pmin, int* __restrict__ pidx) {
    __shared__ float sx[DK * LDX];
    __shared__ float se[DK * LDE];
    const int t = threadIdx.x;
    const int row0 = blockIdx.x * BM;
    const int kbeg = blockIdx.y * KCHUNK;
    const int lane = t & 63, wave = t >> 6;
    const int lm = lane >> 3, ln = lane & 7;
    const int mf = (wave >> 1) * 64 + lm * 8;
    const int nf = (wave & 1) * 64 + ln * 8;
    float xs[8];
    #pragma unroll
    for (int i = 0; i < 8; i++) xs[i] = xsq[row0 + mf + i];
    float rmin[8];
    int ridx[8];
    #pragma unroll
    for (int i = 0; i < 8; i++) { rmin[i] = FLT_MAX; ridx[i] = 0; }
    const int sm = t >> 3;
    const int sd = (t & 7) * 4;
    for (int kt = kbeg; kt < kbeg + KCHUNK; kt += BN) {
        float acc[8][8];
        #pragma unroll
        for (int i = 0; i < 8; i++)
            #pragma unroll
            for (int j = 0; j < 8; j++) acc[i][j] = 0.0f;
        for (int d0 = 0; d0 < D; d0 += DK) {
            __syncthreads();
            #pragma unroll
            for (int r = 0; r < 4; r++) {
                int row = sm + 32 * r;
                float4 v = *(const float4*)(X + (size_t)(row0 + row) * D + d0 + sd);
                sx[(sd + 0) * LDX + row] = v.x;
                sx[(sd + 1) * LDX + row] = v.y;
                sx[(sd + 2) * LDX + row] = v.z;
                sx[(sd + 3) * LDX + row] = v.w;
                float4 ww = *(const float4*)(E + (size_t)(kt + row) * D + d0 + sd);
                se[(sd + 0) * LDE + row] = ww.x;
                se[(sd + 1) * LDE + row] = ww.y;
                se[(sd + 2) * LDE + row] = ww.z;
                se[(sd + 3) * LDE + row] = ww.w;
            }
            __syncthreads();
            #pragma unroll
            for (int d = 0; d < DK; d++) {
                float4 a0 = *(const float4*)(sx + d * LDX + mf);
                float4 a1 = *(const float4*)(sx + d * LDX + mf + 4);
                float4 b0 = *(const float4*)(se + d * LDE + nf);
                float4 b1 = *(const float4*)(se + d * LDE + nf + 4);
                float a[8] = {a0.x, a0.y, a0.z, a0.w, a1.x, a1.y, a1.z, a1.w};
                float b[8] = {b0.x, b0.y, b0.z, b0.w, b1.x, b1.y, b1.z, b1.w};
                #pragma unroll
                for (int i = 0; i < 8; i++)
                    #pragma unroll
                    for (int j = 0; j < 8; j++) acc[i][j] += a[i] * b[j];
            }
        }
        float es[8];
        #pragma unroll
        for (int j = 0; j < 8; j++) es[j] = esq[kt + nf + j];
        #pragma unroll
        for (int i = 0; i < 8; i++)
            #pragma unroll
            for (int j = 0; j < 8; j++) {
                float s = (xs[i] + es[j]) - 2.0f * acc[i][j];
                if (s < rmin[i]) { rmin[i] = s; ridx[i] = kt + nf + j; }
            }
    }
    __syncthreads();
    float* redm = sx;
    int* redi = (int*)se;
    const int c = (wave & 1) * 8 + ln;
    #pragma unroll
    for (int i = 0; i < 8; i++) {
        int r = (wave >> 1) * 64 + lm * 8 + i;
        redm[r * 16 + c] = rmin[i];
        redi[r * 16 + c] = ridx[i];
    }
    __syncthreads();
    if (t < BM) {
        float bst = redm[t * 16];
        int bi = redi[t * 16];
        #pragma unroll
        for (int c2 = 1; c2 < 16; c2++) {
            float v = redm[t * 16 + c2];
            int id = redi[t * 16 + c2];
            if (v < bst || (v == bst && id < bi)) { bst = v; bi = id; }
        }
        pmin[(size_t)(row0 + t) * KSPLIT + blockIdx.y] = bst;
        pidx[(size_t)(row0 + t) * KSPLIT + blockIdx.y] = bi;
    }
}

__global__ void vq_final(const float* __restrict__ E, const float* __restrict__ pmin,
                         const int* __restrict__ pidx, float* __restrict__ out_q,
                         float* __restrict__ out_idx) {
    int row = blockIdx.x;
    int lane = threadIdx.x;
    float bst = pmin[(size_t)row * KSPLIT];
    int bi = pidx[(size_t)row * KSPLIT];
    #pragma unroll
    for (int s = 1; s < KSPLIT; s++) {
        float v = pmin[(size_t)row * KSPLIT + s];
        int id = pidx[(size_t)row * KSPLIT + s];
        if (v < bst || (v == bst && id < bi)) { bst = v; bi = id; }
    }
    if (lane == 0) out_idx[row] = (float)bi;
    float4 v = ((const float4*)(E + (size_t)bi * D))[lane];
    ((float4*)(out_q + (size_t)row * D))[lane] = v;
}

// =======================================================================
extern "C" void kernel_launch(void* const* d_in, const int* in_sizes, int n_in,
                              void* d_out, int out_size, void* d_ws, size_t ws_size,
                              hipStream_t stream) {
    const float* X = (const float*)d_in[0];  // [N, D]
    const float* E = (const float*)d_in[1];  // [K, D]
    float* out_q = (float*)d_out;
    float* out_idx = (float*)d_out + (size_t)N * D;

    // fast-path ws: Xh(8M) Eh(4M) esq(32K) pcand(N*CS*16 = 2M) ~= 14.3MB
    const size_t need = (size_t)12 * 1024 * 1024 + 32768 + (size_t)N * CS * 16;
    if (ws_size >= need) {
        _Float16* Xh = (_Float16*)d_ws;
        _Float16* Eh = Xh + (size_t)N * D;
        float* esq = (float*)(Eh + (size_t)K * D);
        float4* pcand = (float4*)(esq + K);

        vq_prep<<<(N + K) * 32 / 256, 256, 0, stream>>>(X, E, Xh, Eh, esq);
        dim3 grid(N / 512, CS);
        vq_mfma<<<grid, 1024, 0, stream>>>(Xh, Eh, esq, pcand);
        vq_rescore<<<N / 4, 256, 0, stream>>>(X, E, pcand, out_q, out_idx);
    } else {
        float* esq = (float*)d_ws;
        float* xsq = esq + K;
        float* pmin = xsq + N;
        int* pidx = (int*)(pmin + (size_t)N * KSPLIT);
        vq_rowsq<<<K, 64, 0, stream>>>(E, esq);
        vq_rowsq<<<N, 64, 0, stream>>>(X, xsq);
        dim3 grid(N / BM, KSPLIT);
        vq_main<<<grid, 256, 0, stream>>>(X, E, xsq, esq, pmin, pidx);
        vq_final<<<N, 64, 0, stream>>>(E, pmin, pidx, out_q, out_idx);
    }
}

// Round 6
// 144.395 us; speedup vs baseline: 1.6959x; 1.3866x over previous
//
#include <hip/hip_runtime.h>
#include <float.h>
#include <limits.h>
#include <stdint.h>

constexpr int N = 16384;
constexpr int K = 8192;
constexpr int D = 256;

typedef _Float16 half8_t __attribute__((ext_vector_type(8)));
typedef float float4_t __attribute__((ext_vector_type(4)));

// ---------------- fallback helper: row sum-of-squares ----------------
__global__ void vq_rowsq(const float* __restrict__ A, float* __restrict__ out) {
    int row = blockIdx.x;
    int lane = threadIdx.x;  // 64
    float4 v = ((const float4*)(A + (size_t)row * D))[lane];
    float s = v.x * v.x + v.y * v.y + v.z * v.z + v.w * v.w;
    #pragma unroll
    for (int o = 32; o > 0; o >>= 1) s += __shfl_down(s, o);
    if (lane == 0) out[row] = s;
}

// =======================================================================
// FAST PATH (R15): two independent 4-wave blocks per CU.
//   R3's limiter: 8 waves in ONE block, barrier-locked per ctile -> all
//   waves epilogue+drain together, matrix pipe idles. R2/R5 proved >2
//   waves/SIMD impossible (acc+argmin state needs >128 regs). So: same
//   8 waves/CU but TWO blocks (256 thr, 64 KB LDS each) with independent
//   barrier clocks -> phase drift covers epilogue/barrier stalls.
//   E ctile = 64 codes (32 KB) double-buffered; X streamed from global.
//   Eh pre-scaled by -2 (exact), acc initialized from esq: MFMA emits the
//   screen score directly; epilogue is pure cmp/select (validated R4/R5).
// =======================================================================
// Lane-linear tiled layouts (zero bank conflicts, verified R5/R6/R9):
//   Xh[rt*4096 + ds*512 + g*64 + q*16 + r15] chunks (g=localrow>>4)
//   Eh[(ct8*8+ds)*512 + (lc>>4)*64 + q*16 + (lc&15)] chunks (lc=code&127)
// chunk = 16B (8 halves); q = dim-quad within the 32-dim step ds.
// A 64-code ctile (half h of 128-code tile ct8) = chunks [h*256, h*256+256)
// of each ds-group: contiguous, same inner layout. Eh stores -2*E.

__global__ void vq_prep(const float* __restrict__ X, const float* __restrict__ E,
                        _Float16* __restrict__ Xh, _Float16* __restrict__ Eh,
                        float* __restrict__ esq) {
    int c = blockIdx.x * 256 + threadIdx.x;
    const int XCH = N * 32;  // X chunks; % 256 == 0 so blocks don't mix X/E
    if (c < XCH) {
        int row = c >> 5, q8 = c & 31;
        int ds = q8 >> 2, q = q8 & 3;
        int rt = row >> 7, lr = row & 127;
        int slot = ((lr >> 4) << 6) + (q << 4) + (lr & 15);
        size_t dst = ((size_t)rt * 4096 + ds * 512 + slot) * 8;
        const float4* s4 = (const float4*)(X + (size_t)row * D + q8 * 8);
        float4 v0 = s4[0], v1 = s4[1];
        float x[8] = {v0.x, v0.y, v0.z, v0.w, v1.x, v1.y, v1.z, v1.w};
        half8_t hh;
        #pragma unroll
        for (int i = 0; i < 8; i++) hh[i] = (_Float16)x[i];
        *(half8_t*)(Xh + dst) = hh;
    } else {
        int cc = c - XCH;
        int code = cc >> 5, q8 = cc & 31;
        int ds = q8 >> 2, q = q8 & 3;
        int ct = code >> 7, lc = code & 127;
        int slot = ((lc >> 4) << 6) + (q << 4) + (lc & 15);
        size_t dst = ((size_t)(ct * 8 + ds) * 512 + slot) * 8;
        const float4* s4 = (const float4*)(E + (size_t)code * D + q8 * 8);
        float4 v0 = s4[0], v1 = s4[1];
        float x[8] = {v0.x, v0.y, v0.z, v0.w, v1.x, v1.y, v1.z, v1.w};
        half8_t hh;
        float sq = 0.f;
        #pragma unroll
        for (int i = 0; i < 8; i++) {
            sq += x[i] * x[i];
            hh[i] = (_Float16)(-2.0f * x[i]);  // exact 2^1 scale of (f16)x
        }
        *(half8_t*)(Eh + dst) = hh;
        #pragma unroll
        for (int o = 16; o > 0; o >>= 1) sq += __shfl_xor(sq, o);
        if ((threadIdx.x & 31) == 0) esq[code] = sq;
    }
}

__device__ __forceinline__ void ldg_lds16(const _Float16* g, _Float16* l) {
    __builtin_amdgcn_global_load_lds(
        (const __attribute__((address_space(1))) unsigned int*)g,
        (__attribute__((address_space(3))) unsigned int*)l, 16, 0, 0);
}

constexpr int CS = 8;    // code split; block owns K/CS = 1024 codes
constexpr int KT = 16;   // 16 64-code ctiles per block

// block: 256 thr = 4 waves, rows slice = 256 (wave w owns 64 rows), codes
// 1024 in 16 x 64-code ctiles. Wave tile 64x64: acc[4][4] (64 regs) +
// best/bidx[16] + frags ~= 176 regs total -> no spill at 8 waves/CU.
// E ctile 32 KB double-buffered (64 KB LDS) -> 2 blocks/CU, independent
// barriers -> cross-block phase drift feeds the matrix pipe during the
// other block's epilogue/drain. X streamed from global (L2-resident).
__global__ __launch_bounds__(256, 2) void vq_mfma(
    const _Float16* __restrict__ Xh, const _Float16* __restrict__ Eh,
    const float* __restrict__ esq, float4* __restrict__ pcand) {
    __shared__ _Float16 lds[32768];  // 2 bufs x 2048 chunks x 16B = 64 KB

    const int t = threadIdx.x, w = t >> 6, lane = t & 63;
    const int rs = blockIdx.x;  // row slice 0..63 (256 rows each)
    const int cs = blockIdx.y;  // code split 0..7
    const int c15 = lane & 15, quad = lane >> 4;

    float best[16];
    int bidx[16];
    #pragma unroll
    for (int i = 0; i < 16; i++) { best[i] = FLT_MAX; bidx[i] = 0; }

    // X chunks (global): wave rows = rs*256 + w*64
    //   rt = rs*2 + (w>>1), half hr = w&1 -> chunk offset hr*256
    const half8_t* Xg = (const half8_t*)Xh +
        ((size_t)(rs * 2 + (w >> 1)) * 4096 + (w & 1) * 256 + lane);

    // stage 64-code ctile ct into LDS buf b: ct8 = cs*8 + (ct>>1), h = ct&1.
    // wave w copies ds-groups {2w, 2w+1}: 2 x 4 x global_load_lds 16B/lane.
    auto stage = [&](int ct, int b) {
        const int ct8 = cs * 8 + (ct >> 1);
        const int h = ct & 1;
        const half8_t* src = (const half8_t*)Eh +
            ((size_t)ct8 * 4096 + h * 256 + lane);
        _Float16* dst = lds + (size_t)b * 2048 * 8;
        #pragma unroll
        for (int dd = 0; dd < 2; dd++) {
            const int ds = 2 * w + dd;
            #pragma unroll
            for (int i = 0; i < 4; i++)
                ldg_lds16((const _Float16*)(src + (size_t)ds * 512 + i * 64),
                          dst + (ds * 256 + i * 64) * 8);
        }
    };

    float4_t acc[4][4];
    float eqc[4], eqn[4];

    stage(0, 0);
    {
        const int code0 = cs * 1024;
        #pragma unroll
        for (int nt = 0; nt < 4; nt++) eqc[nt] = esq[code0 + nt * 16 + c15];
    }
    __syncthreads();  // buf0 ready

    for (int ct = 0; ct < KT; ct++) {
        if (ct + 1 < KT) {
            stage(ct + 1, (ct + 1) & 1);  // prefetch next ctile (other buf)
            const int code1 = cs * 1024 + (ct + 1) * 64;
            #pragma unroll
            for (int nt = 0; nt < 4; nt++) eqn[nt] = esq[code1 + nt * 16 + c15];
        }

        // init acc = esq: MFMA chain then yields sc = eq + sum(-2e*x)
        #pragma unroll
        for (int mt = 0; mt < 4; mt++)
            #pragma unroll
            for (int nt = 0; nt < 4; nt++)
                #pragma unroll
                for (int r = 0; r < 4; r++) acc[mt][nt][r] = eqc[nt];

        const half8_t* Cc = (const half8_t*)lds + (size_t)((ct & 1) * 2048);

        #pragma unroll
        for (int ds = 0; ds < 8; ds++) {
            half8_t Xf[4], Ef[4];
            #pragma unroll
            for (int mt = 0; mt < 4; mt++) Xf[mt] = Xg[ds * 512 + mt * 64];
            #pragma unroll
            for (int nt = 0; nt < 4; nt++) Ef[nt] = Cc[ds * 256 + nt * 64 + lane];

            __builtin_amdgcn_s_setprio(1);
            #pragma unroll
            for (int mt = 0; mt < 4; mt++)
                #pragma unroll
                for (int nt = 0; nt < 4; nt++)
                    acc[mt][nt] = __builtin_amdgcn_mfma_f32_16x16x32_f16(
                        Xf[mt], Ef[nt], acc[mt][nt], 0, 0, 0);
            __builtin_amdgcn_s_setprio(0);
        }

        // ctile epilogue: pure min-update (scores complete in acc)
        const int code0 = cs * 1024 + ct * 64;
        #pragma unroll
        for (int nt = 0; nt < 4; nt++) {
            const int code = code0 + nt * 16 + c15;
            #pragma unroll
            for (int mt = 0; mt < 4; mt++)
                #pragma unroll
                for (int rg = 0; rg < 4; rg++) {
                    float sc = acc[mt][nt][rg];
                    int sl = mt * 4 + rg;
                    if (sc < best[sl]) { best[sl] = sc; bidx[sl] = code; }
                }
        }
        eqc[0] = eqn[0]; eqc[1] = eqn[1];
        eqc[2] = eqn[2]; eqc[3] = eqn[3];

        __syncthreads();  // all waves done reading buf[ct&1]; next staged
    }

    // per-row top-2 over 16 contributors (c15 lanes); LDS reused
    float* smin = (float*)lds;         // [16][256] = 16 KB
    int* sidx = (int*)lds + 4096;      // [16][256] = 16 KB
    #pragma unroll
    for (int sl = 0; sl < 16; sl++) {
        int row = w * 64 + (sl >> 2) * 16 + quad * 4 + (sl & 3);
        smin[c15 * 256 + row] = best[sl];
        sidx[c15 * 256 + row] = bidx[sl];
    }
    __syncthreads();
    {
        float m1 = FLT_MAX, m2 = FLT_MAX;
        int i1 = 0, i2 = 0;
        for (int c = 0; c < 16; c++) {
            float v = smin[c * 256 + t];
            int id = sidx[c * 256 + t];
            if (v < m1 || (v == m1 && id < i1)) {
                m2 = m1; i2 = i1; m1 = v; i1 = id;
            } else if (v < m2 || (v == m2 && id < i2)) {
                m2 = v; i2 = id;
            }
        }
        uint32_t pk = ((uint32_t)i1 << 13) | (uint32_t)(i2 & 8191);
        float4 out;
        out.x = m1; out.y = m2; out.z = __int_as_float((int)pk); out.w = 0.f;
        pcand[(size_t)(rs * 256 + t) * CS + cs] = out;
    }
}

__device__ __forceinline__ float wave_sum(float v) {
    #pragma unroll
    for (int o = 1; o < 64; o <<= 1) v += __shfl_xor(v, o);
    return v;
}

// margin-gated final. Screen err bound per score ~0.14 (10-sigma); EB=0.4.
// gap > EB: screen winner provably exact. Else: exact-fp32 rescore of only
// candidates with screened score <= gm1 + EB.
__global__ void vq_rescore(const float* __restrict__ X, const float* __restrict__ E,
                           const float4* __restrict__ pcand, float* __restrict__ out_q,
                           float* __restrict__ out_idx) {
    constexpr float EB = 0.4f;
    int row = blockIdx.x * 4 + (threadIdx.x >> 6);
    int lane = threadIdx.x & 63;

    int cand[2 * CS];
    float csc[2 * CS];
    float gm1 = FLT_MAX, gm2 = FLT_MAX;
    int gi1 = INT_MAX;
    #pragma unroll
    for (int s = 0; s < CS; s++) {
        float4 p = pcand[(size_t)row * CS + s];
        uint32_t pk = (uint32_t)__float_as_int(p.z);
        int i1 = (int)(pk >> 13), i2 = (int)(pk & 8191);
        cand[2 * s] = i1;
        csc[2 * s] = p.x;
        cand[2 * s + 1] = i2;
        csc[2 * s + 1] = p.y;
        if (p.x < gm1 || (p.x == gm1 && i1 < gi1)) {
            gm2 = gm1; gm1 = p.x; gi1 = i1;
        } else if (p.x < gm2) gm2 = p.x;
        if (p.y < gm2) gm2 = p.y;
    }

    int besti = gi1;
    if (gm2 - gm1 <= EB) {  // ambiguous: exact fp32 rescore of survivors
        float4 xv = ((const float4*)(X + (size_t)row * D))[lane];
        float xs = wave_sum(xv.x * xv.x + xv.y * xv.y + xv.z * xv.z + xv.w * xv.w);
        float bestv = FLT_MAX;
        besti = INT_MAX;
        for (int c = 0; c < 2 * CS; c++) {
            if (csc[c] > gm1 + EB) continue;  // cannot be the true winner
            int idx = cand[c];
            float4 e = ((const float4*)(E + (size_t)idx * D))[lane];
            float dp = wave_sum(xv.x * e.x + xv.y * e.y + xv.z * e.z + xv.w * e.w);
            float eq = wave_sum(e.x * e.x + e.y * e.y + e.z * e.z + e.w * e.w);
            float sc = (xs + eq) - 2.f * dp;
            if (sc < bestv || (sc == bestv && idx < besti)) { bestv = sc; besti = idx; }
        }
    }
    if (lane == 0) out_idx[row] = (float)besti;
    float4 bv = ((const float4*)(E + (size_t)besti * D))[lane];
    ((float4*)(out_q + (size_t)row * D))[lane] = bv;
}

// =======================================================================
// FALLBACK (proven R1 fp32 path) — used only if ws_size is too small
// =======================================================================
constexpr int BM = 128, BN = 128, DK = 32, KSPLIT = 8;
constexpr int KCHUNK = K / KSPLIT;
constexpr int LDX = BM + 4, LDE = BN + 4;

__global__ __launch_bounds__(256) void vq_main(
    const float* __restrict__ X, const float* __restrict__ E,
    const float* __restrict__ xsq, const float* __restrict__ esq,
    float* __restrict__ pmin, int* __restrict__ pidx) {
    __shared__ float sx[DK * LDX];
    __shared__ float se[DK * LDE];
    const int t = threadIdx.x;
    const int row0 = blockIdx.x * BM;
    const int kbeg = blockIdx.y * KCHUNK;
    const int lane = t & 63, wave = t >> 6;
    const int lm = lane >> 3, ln = lane & 7;
    const int mf = (wave >> 1) * 64 + lm * 8;
    const int nf = (wave & 1) * 64 + ln * 8;
    float xs[8];
    #pragma unroll
    for (int i = 0; i < 8; i++) xs[i] = xsq[row0 + mf + i];
    float rmin[8];
    int ridx[8];
    #pragma unroll
    for (int i = 0; i < 8; i++) { rmin[i] = FLT_MAX; ridx[i] = 0; }
    const int sm = t >> 3;
    const int sd = (t & 7) * 4;
    for (int kt = kbeg; kt < kbeg + KCHUNK; kt += BN) {
        float acc[8][8];
        #pragma unroll
        for (int i = 0; i < 8; i++)
            #pragma unroll
            for (int j = 0; j < 8; j++) acc[i][j] = 0.0f;
        for (int d0 = 0; d0 < D; d0 += DK) {
            __syncthreads();
            #pragma unroll
            for (int r = 0; r < 4; r++) {
                int row = sm + 32 * r;
                float4 v = *(const float4*)(X + (size_t)(row0 + row) * D + d0 + sd);
                sx[(sd + 0) * LDX + row] = v.x;
                sx[(sd + 1) * LDX + row] = v.y;
                sx[(sd + 2) * LDX + row] = v.z;
                sx[(sd + 3) * LDX + row] = v.w;
                float4 ww = *(const float4*)(E + (size_t)(kt + row) * D + d0 + sd);
                se[(sd + 0) * LDE + row] = ww.x;
                se[(sd + 1) * LDE + row] = ww.y;
                se[(sd + 2) * LDE + row] = ww.z;
                se[(sd + 3) * LDE + row] = ww.w;
            }
            __syncthreads();
            #pragma unroll
            for (int d = 0; d < DK; d++) {
                float4 a0 = *(const float4*)(sx + d * LDX + mf);
                float4 a1 = *(const float4*)(sx + d * LDX + mf + 4);
                float4 b0 = *(const float4*)(se + d * LDE + nf);
                float4 b1 = *(const float4*)(se + d * LDE + nf + 4);
                float a[8] = {a0.x, a0.y, a0.z, a0.w, a1.x, a1.y, a1.z, a1.w};
                float b[8] = {b0.x, b0.y, b0.z, b0.w, b1.x, b1.y, b1.z, b1.w};
                #pragma unroll
                for (int i = 0; i < 8; i++)
                    #pragma unroll
                    for (int j = 0; j < 8; j++) acc[i][j] += a[i] * b[j];
            }
        }
        float es[8];
        #pragma unroll
        for (int j = 0; j < 8; j++) es[j] = esq[kt + nf + j];
        #pragma unroll
        for (int i = 0; i < 8; i++)
            #pragma unroll
            for (int j = 0; j < 8; j++) {
                float s = (xs[i] + es[j]) - 2.0f * acc[i][j];
                if (s < rmin[i]) { rmin[i] = s; ridx[i] = kt + nf + j; }
            }
    }
    __syncthreads();
    float* redm = sx;
    int* redi = (int*)se;
    const int c = (wave & 1) * 8 + ln;
    #pragma unroll
    for (int i = 0; i < 8; i++) {
        int r = (wave >> 1) * 64 + lm * 8 + i;
        redm[r * 16 + c] = rmin[i];
        redi[r * 16 + c] = ridx[i];
    }
    __syncthreads();
    if (t < BM) {
        float bst = redm[t * 16];
        int bi = redi[t * 16];
        #pragma unroll
        for (int c2 = 1; c2 < 16; c2++) {
            float v = redm[t * 16 + c2];
            int id = redi[t * 16 + c2];
            if (v < bst || (v == bst && id < bi)) { bst = v; bi = id; }
        }
        pmin[(size_t)(row0 + t) * KSPLIT + blockIdx.y] = bst;
        pidx[(size_t)(row0 + t) * KSPLIT + blockIdx.y] = bi;
    }
}

__global__ void vq_final(const float* __restrict__ E, const float* __restrict__ pmin,
                         const int* __restrict__ pidx, float* __restrict__ out_q,
                         float* __restrict__ out_idx) {
    int row = blockIdx.x;
    int lane = threadIdx.x;
    float bst = pmin[(size_t)row * KSPLIT];
    int bi = pidx[(size_t)row * KSPLIT];
    #pragma unroll
    for (int s = 1; s < KSPLIT; s++) {
        float v = pmin[(size_t)row * KSPLIT + s];
        int id = pidx[(size_t)row * KSPLIT + s];
        if (v < bst || (v == bst && id < bi)) { bst = v; bi = id; }
    }
    if (lane == 0) out_idx[row] = (float)bi;
    float4 v = ((const float4*)(E + (size_t)bi * D))[lane];
    ((float4*)(out_q + (size_t)row * D))[lane] = v;
}

// =======================================================================
extern "C" void kernel_launch(void* const* d_in, const int* in_sizes, int n_in,
                              void* d_out, int out_size, void* d_ws, size_t ws_size,
                              hipStream_t stream) {
    const float* X = (const float*)d_in[0];  // [N, D]
    const float* E = (const float*)d_in[1];  // [K, D]
    float* out_q = (float*)d_out;
    float* out_idx = (float*)d_out + (size_t)N * D;

    // fast-path ws: Xh(8M) Eh(4M) esq(32K) pcand(N*CS*16 = 2M) ~= 14.3MB
    const size_t need = (size_t)12 * 1024 * 1024 + 32768 + (size_t)N * CS * 16;
    if (ws_size >= need) {
        _Float16* Xh = (_Float16*)d_ws;
        _Float16* Eh = Xh + (size_t)N * D;
        float* esq = (float*)(Eh + (size_t)K * D);
        float4* pcand = (float4*)(esq + K);

        vq_prep<<<(N + K) * 32 / 256, 256, 0, stream>>>(X, E, Xh, Eh, esq);
        dim3 grid(N / 256, CS);
        vq_mfma<<<grid, 256, 0, stream>>>(Xh, Eh, esq, pcand);
        vq_rescore<<<N / 4, 256, 0, stream>>>(X, E, pcand, out_q, out_idx);
    } else {
        float* esq = (float*)d_ws;
        float* xsq = esq + K;
        float* pmin = xsq + N;
        int* pidx = (int*)(pmin + (size_t)N * KSPLIT);
        vq_rowsq<<<K, 64, 0, stream>>>(E, esq);
        vq_rowsq<<<N, 64, 0, stream>>>(X, xsq);
        dim3 grid(N / BM, KSPLIT);
        vq_main<<<grid, 256, 0, stream>>>(X, E, xsq, esq, pmin, pidx);
        vq_final<<<N, 64, 0, stream>>>(E, pmin, pidx, out_q, out_idx);
    }
}

// Round 7
// 142.771 us; speedup vs baseline: 1.7152x; 1.0114x over previous
//
#include <hip/hip_runtime.h>
#include <float.h>
#include <limits.h>
#include <stdint.h>

constexpr int N = 16384;
constexpr int K = 8192;
constexpr int D = 256;

typedef _Float16 half8_t __attribute__((ext_vector_type(8)));
typedef float float4_t __attribute__((ext_vector_type(4)));

// ---------------- fallback helper: row sum-of-squares ----------------
__global__ void vq_rowsq(const float* __restrict__ A, float* __restrict__ out) {
    int row = blockIdx.x;
    int lane = threadIdx.x;  // 64
    float4 v = ((const float4*)(A + (size_t)row * D))[lane];
    float s = v.x * v.x + v.y * v.y + v.z * v.z + v.w * v.w;
    #pragma unroll
    for (int o = 32; o > 0; o >>= 1) s += __shfl_down(s, o);
    if (lane == 0) out[row] = s;
}

// =======================================================================
// FAST PATH (R16): R6 mfma kernel UNCHANGED (61.9us, MfmaUtil 47%, best).
// This round attacks the ~82us residual outside vq_mfma: vq_prep was
// src-major (coalesced 32B reads, SCATTERED 16B writes at 8KB stride ->
// terrible write-line utilization on 12MB of output). R16 inverts prep
// to DST-major: thread = destination chunk; writes are perfectly linear
// (1KB/wave), inverse-mapped reads are 16 rows x 128B contiguous segments
// (100% line utilization). Output bytes bit-identical (pure permutation
// of the work assignment). esq moves to a 3rd grid section of the same
// kernel (64-lane rowsq; summation-order change ~1e-6, absorbed by EB).
// =======================================================================
// Lane-linear tiled layouts (zero bank conflicts, verified R5/R6/R9):
//   Xh[rt*4096 + ds*512 + g*64 + q*16 + r15] chunks (g=localrow>>4)
//   Eh[(ct8*8+ds)*512 + (lc>>4)*64 + q*16 + (lc&15)] chunks (lc=code&127)
// chunk = 16B (8 halves); q = dim-quad within the 32-dim step ds.
// Eh stores -2*E (exact power-of-2 scale; esq kept true fp32).

__global__ void vq_prep(const float* __restrict__ X, const float* __restrict__ E,
                        _Float16* __restrict__ Xh, _Float16* __restrict__ Eh,
                        float* __restrict__ esq) {
    constexpr int XB = (N * 32) / 256;   // 2048 blocks: X dst-major
    constexpr int EBK = (K * 32) / 256;  // 1024 blocks: E dst-major
    const int b = blockIdx.x, t = threadIdx.x;
    if (b < XB) {
        const int c = b * 256 + t;              // dst chunk index
        const int rt = c >> 12, rem = c & 4095;
        const int ds = rem >> 9, slot = rem & 511;
        const int g = slot >> 6, q = (slot >> 4) & 3, r15 = slot & 15;
        const int row = rt * 128 + g * 16 + r15;
        const int q8 = ds * 4 + q;
        const float4* s4 = (const float4*)(X + (size_t)row * D + q8 * 8);
        float4 v0 = s4[0], v1 = s4[1];
        float x[8] = {v0.x, v0.y, v0.z, v0.w, v1.x, v1.y, v1.z, v1.w};
        half8_t hh;
        #pragma unroll
        for (int i = 0; i < 8; i++) hh[i] = (_Float16)x[i];
        *(half8_t*)(Xh + (size_t)c * 8) = hh;   // linear 1KB/wave store
    } else if (b < XB + EBK) {
        const int cc = (b - XB) * 256 + t;      // dst chunk index
        const int ct = cc >> 12, rem = cc & 4095;
        const int ds = rem >> 9, slot = rem & 511;
        const int g = slot >> 6, q = (slot >> 4) & 3, r15 = slot & 15;
        const int code = ct * 128 + g * 16 + r15;
        const int q8 = ds * 4 + q;
        const float4* s4 = (const float4*)(E + (size_t)code * D + q8 * 8);
        float4 v0 = s4[0], v1 = s4[1];
        float x[8] = {v0.x, v0.y, v0.z, v0.w, v1.x, v1.y, v1.z, v1.w};
        half8_t hh;
        #pragma unroll
        for (int i = 0; i < 8; i++)
            hh[i] = (_Float16)(-2.0f * x[i]);   // exact 2^1 scale of (f16)x
        *(half8_t*)(Eh + (size_t)cc * 8) = hh;  // linear 1KB/wave store
    } else {
        // esq section: 2048 blocks x 4 codes (64 lanes per code)
        const int eb = b - XB - EBK;
        const int code = eb * 4 + (t >> 6);
        const int lane = t & 63;
        float4 v = ((const float4*)(E + (size_t)code * D))[lane];
        float s = v.x * v.x + v.y * v.y + v.z * v.z + v.w * v.w;
        #pragma unroll
        for (int o = 32; o > 0; o >>= 1) s += __shfl_xor(s, o);
        if (lane == 0) esq[code] = s;
    }
}

__device__ __forceinline__ void ldg_lds16(const _Float16* g, _Float16* l) {
    __builtin_amdgcn_global_load_lds(
        (const __attribute__((address_space(1))) unsigned int*)g,
        (__attribute__((address_space(3))) unsigned int*)l, 16, 0, 0);
}

constexpr int CS = 8;    // code split; block owns K/CS = 1024 codes
constexpr int KT = 16;   // 16 64-code ctiles per block

// block: 256 thr = 4 waves, rows slice = 256 (wave w owns 64 rows), codes
// 1024 in 16 x 64-code ctiles. Wave tile 64x64: acc[4][4] (64 regs) +
// best/bidx[16] + frags ~= 176 regs total -> no spill at 8 waves/CU.
// E ctile 32 KB double-buffered (64 KB LDS) -> 2 blocks/CU, independent
// barriers -> cross-block phase drift feeds the matrix pipe during the
// other block's epilogue/drain. X streamed from global (L2-resident).
__global__ __launch_bounds__(256, 2) void vq_mfma(
    const _Float16* __restrict__ Xh, const _Float16* __restrict__ Eh,
    const float* __restrict__ esq, float4* __restrict__ pcand) {
    __shared__ _Float16 lds[32768];  // 2 bufs x 2048 chunks x 16B = 64 KB

    const int t = threadIdx.x, w = t >> 6, lane = t & 63;
    const int rs = blockIdx.x;  // row slice 0..63 (256 rows each)
    const int cs = blockIdx.y;  // code split 0..7
    const int c15 = lane & 15, quad = lane >> 4;

    float best[16];
    int bidx[16];
    #pragma unroll
    for (int i = 0; i < 16; i++) { best[i] = FLT_MAX; bidx[i] = 0; }

    // X chunks (global): wave rows = rs*256 + w*64
    //   rt = rs*2 + (w>>1), half hr = w&1 -> chunk offset hr*256
    const half8_t* Xg = (const half8_t*)Xh +
        ((size_t)(rs * 2 + (w >> 1)) * 4096 + (w & 1) * 256 + lane);

    // stage 64-code ctile ct into LDS buf b: ct8 = cs*8 + (ct>>1), h = ct&1.
    // wave w copies ds-groups {2w, 2w+1}: 2 x 4 x global_load_lds 16B/lane.
    auto stage = [&](int ct, int b) {
        const int ct8 = cs * 8 + (ct >> 1);
        const int h = ct & 1;
        const half8_t* src = (const half8_t*)Eh +
            ((size_t)ct8 * 4096 + h * 256 + lane);
        _Float16* dst = lds + (size_t)b * 2048 * 8;
        #pragma unroll
        for (int dd = 0; dd < 2; dd++) {
            const int ds = 2 * w + dd;
            #pragma unroll
            for (int i = 0; i < 4; i++)
                ldg_lds16((const _Float16*)(src + (size_t)ds * 512 + i * 64),
                          dst + (ds * 256 + i * 64) * 8);
        }
    };

    float4_t acc[4][4];
    float eqc[4], eqn[4];

    stage(0, 0);
    {
        const int code0 = cs * 1024;
        #pragma unroll
        for (int nt = 0; nt < 4; nt++) eqc[nt] = esq[code0 + nt * 16 + c15];
    }
    __syncthreads();  // buf0 ready

    for (int ct = 0; ct < KT; ct++) {
        if (ct + 1 < KT) {
            stage(ct + 1, (ct + 1) & 1);  // prefetch next ctile (other buf)
            const int code1 = cs * 1024 + (ct + 1) * 64;
            #pragma unroll
            for (int nt = 0; nt < 4; nt++) eqn[nt] = esq[code1 + nt * 16 + c15];
        }

        // init acc = esq: MFMA chain then yields sc = eq + sum(-2e*x)
        #pragma unroll
        for (int mt = 0; mt < 4; mt++)
            #pragma unroll
            for (int nt = 0; nt < 4; nt++)
                #pragma unroll
                for (int r = 0; r < 4; r++) acc[mt][nt][r] = eqc[nt];

        const half8_t* Cc = (const half8_t*)lds + (size_t)((ct & 1) * 2048);

        #pragma unroll
        for (int ds = 0; ds < 8; ds++) {
            half8_t Xf[4], Ef[4];
            #pragma unroll
            for (int mt = 0; mt < 4; mt++) Xf[mt] = Xg[ds * 512 + mt * 64];
            #pragma unroll
            for (int nt = 0; nt < 4; nt++) Ef[nt] = Cc[ds * 256 + nt * 64 + lane];

            __builtin_amdgcn_s_setprio(1);
            #pragma unroll
            for (int mt = 0; mt < 4; mt++)
                #pragma unroll
                for (int nt = 0; nt < 4; nt++)
                    acc[mt][nt] = __builtin_amdgcn_mfma_f32_16x16x32_f16(
                        Xf[mt], Ef[nt], acc[mt][nt], 0, 0, 0);
            __builtin_amdgcn_s_setprio(0);
        }

        // ctile epilogue: pure min-update (scores complete in acc)
        const int code0 = cs * 1024 + ct * 64;
        #pragma unroll
        for (int nt = 0; nt < 4; nt++) {
            const int code = code0 + nt * 16 + c15;
            #pragma unroll
            for (int mt = 0; mt < 4; mt++)
                #pragma unroll
                for (int rg = 0; rg < 4; rg++) {
                    float sc = acc[mt][nt][rg];
                    int sl = mt * 4 + rg;
                    if (sc < best[sl]) { best[sl] = sc; bidx[sl] = code; }
                }
        }
        eqc[0] = eqn[0]; eqc[1] = eqn[1];
        eqc[2] = eqn[2]; eqc[3] = eqn[3];

        __syncthreads();  // all waves done reading buf[ct&1]; next staged
    }

    // per-row top-2 over 16 contributors (c15 lanes); LDS reused
    float* smin = (float*)lds;         // [16][256] = 16 KB
    int* sidx = (int*)lds + 4096;      // [16][256] = 16 KB
    #pragma unroll
    for (int sl = 0; sl < 16; sl++) {
        int row = w * 64 + (sl >> 2) * 16 + quad * 4 + (sl & 3);
        smin[c15 * 256 + row] = best[sl];
        sidx[c15 * 256 + row] = bidx[sl];
    }
    __syncthreads();
    {
        float m1 = FLT_MAX, m2 = FLT_MAX;
        int i1 = 0, i2 = 0;
        for (int c = 0; c < 16; c++) {
            float v = smin[c * 256 + t];
            int id = sidx[c * 256 + t];
            if (v < m1 || (v == m1 && id < i1)) {
                m2 = m1; i2 = i1; m1 = v; i1 = id;
            } else if (v < m2 || (v == m2 && id < i2)) {
                m2 = v; i2 = id;
            }
        }
        uint32_t pk = ((uint32_t)i1 << 13) | (uint32_t)(i2 & 8191);
        float4 out;
        out.x = m1; out.y = m2; out.z = __int_as_float((int)pk); out.w = 0.f;
        pcand[(size_t)(rs * 256 + t) * CS + cs] = out;
    }
}

__device__ __forceinline__ float wave_sum(float v) {
    #pragma unroll
    for (int o = 1; o < 64; o <<= 1) v += __shfl_xor(v, o);
    return v;
}

// margin-gated final. Screen err bound per score ~0.14 (10-sigma); EB=0.4.
// gap > EB: screen winner provably exact. Else: exact-fp32 rescore of only
// candidates with screened score <= gm1 + EB.
__global__ void vq_rescore(const float* __restrict__ X, const float* __restrict__ E,
                           const float4* __restrict__ pcand, float* __restrict__ out_q,
                           float* __restrict__ out_idx) {
    constexpr float EB = 0.4f;
    int row = blockIdx.x * 4 + (threadIdx.x >> 6);
    int lane = threadIdx.x & 63;

    int cand[2 * CS];
    float csc[2 * CS];
    float gm1 = FLT_MAX, gm2 = FLT_MAX;
    int gi1 = INT_MAX;
    #pragma unroll
    for (int s = 0; s < CS; s++) {
        float4 p = pcand[(size_t)row * CS + s];
        uint32_t pk = (uint32_t)__float_as_int(p.z);
        int i1 = (int)(pk >> 13), i2 = (int)(pk & 8191);
        cand[2 * s] = i1;
        csc[2 * s] = p.x;
        cand[2 * s + 1] = i2;
        csc[2 * s + 1] = p.y;
        if (p.x < gm1 || (p.x == gm1 && i1 < gi1)) {
            gm2 = gm1; gm1 = p.x; gi1 = i1;
        } else if (p.x < gm2) gm2 = p.x;
        if (p.y < gm2) gm2 = p.y;
    }

    int besti = gi1;
    if (gm2 - gm1 <= EB) {  // ambiguous: exact fp32 rescore of survivors
        float4 xv = ((const float4*)(X + (size_t)row * D))[lane];
        float xs = wave_sum(xv.x * xv.x + xv.y * xv.y + xv.z * xv.z + xv.w * xv.w);
        float bestv = FLT_MAX;
        besti = INT_MAX;
        for (int c = 0; c < 2 * CS; c++) {
            if (csc[c] > gm1 + EB) continue;  // cannot be the true winner
            int idx = cand[c];
            float4 e = ((const float4*)(E + (size_t)idx * D))[lane];
            float dp = wave_sum(xv.x * e.x + xv.y * e.y + xv.z * e.z + xv.w * e.w);
            float eq = wave_sum(e.x * e.x + e.y * e.y + e.z * e.z + e.w * e.w);
            float sc = (xs + eq) - 2.f * dp;
            if (sc < bestv || (sc == bestv && idx < besti)) { bestv = sc; besti = idx; }
        }
    }
    if (lane == 0) out_idx[row] = (float)besti;
    float4 bv = ((const float4*)(E + (size_t)besti * D))[lane];
    ((float4*)(out_q + (size_t)row * D))[lane] = bv;
}

// =======================================================================
// FALLBACK (proven R1 fp32 path) — used only if ws_size is too small
// =======================================================================
constexpr int BM = 128, BN = 128, DK = 32, KSPLIT = 8;
constexpr int KCHUNK = K / KSPLIT;
constexpr int LDX = BM + 4, LDE = BN + 4;

__global__ __launch_bounds__(256) void vq_main(
    const float* __restrict__ X, const float* __restrict__ E,
    const float* __restrict__ xsq, const float* __restrict__ esq,
    float* __restrict__ pmin, int* __restrict__ pidx) {
    __shared__ float sx[DK * LDX];
    __shared__ float se[DK * LDE];
    const int t = threadIdx.x;
    const int row0 = blockIdx.x * BM;
    const int kbeg = blockIdx.y * KCHUNK;
    const int lane = t & 63, wave = t >> 6;
    const int lm = lane >> 3, ln = lane & 7;
    const int mf = (wave >> 1) * 64 + lm * 8;
    const int nf = (wave & 1) * 64 + ln * 8;
    float xs[8];
    #pragma unroll
    for (int i = 0; i < 8; i++) xs[i] = xsq[row0 + mf + i];
    float rmin[8];
    int ridx[8];
    #pragma unroll
    for (int i = 0; i < 8; i++) { rmin[i] = FLT_MAX; ridx[i] = 0; }
    const int sm = t >> 3;
    const int sd = (t & 7) * 4;
    for (int kt = kbeg; kt < kbeg + KCHUNK; kt += BN) {
        float acc[8][8];
        #pragma unroll
        for (int i = 0; i < 8; i++)
            #pragma unroll
            for (int j = 0; j < 8; j++) acc[i][j] = 0.0f;
        for (int d0 = 0; d0 < D; d0 += DK) {
            __syncthreads();
            #pragma unroll
            for (int r = 0; r < 4; r++) {
                int row = sm + 32 * r;
                float4 v = *(const float4*)(X + (size_t)(row0 + row) * D + d0 + sd);
                sx[(sd + 0) * LDX + row] = v.x;
                sx[(sd + 1) * LDX + row] = v.y;
                sx[(sd + 2) * LDX + row] = v.z;
                sx[(sd + 3) * LDX + row] = v.w;
                float4 ww = *(const float4*)(E + (size_t)(kt + row) * D + d0 + sd);
                se[(sd + 0) * LDE + row] = ww.x;
                se[(sd + 1) * LDE + row] = ww.y;
                se[(sd + 2) * LDE + row] = ww.z;
                se[(sd + 3) * LDE + row] = ww.w;
            }
            __syncthreads();
            #pragma unroll
            for (int d = 0; d < DK; d++) {
                float4 a0 = *(const float4*)(sx + d * LDX + mf);
                float4 a1 = *(const float4*)(sx + d * LDX + mf + 4);
                float4 b0 = *(const float4*)(se + d * LDE + nf);
                float4 b1 = *(const float4*)(se + d * LDE + nf + 4);
                float a[8] = {a0.x, a0.y, a0.z, a0.w, a1.x, a1.y, a1.z, a1.w};
                float b[8] = {b0.x, b0.y, b0.z, b0.w, b1.x, b1.y, b1.z, b1.w};
                #pragma unroll
                for (int i = 0; i < 8; i++)
                    #pragma unroll
                    for (int j = 0; j < 8; j++) acc[i][j] += a[i] * b[j];
            }
        }
        float es[8];
        #pragma unroll
        for (int j = 0; j < 8; j++) es[j] = esq[kt + nf + j];
        #pragma unroll
        for (int i = 0; i < 8; i++)
            #pragma unroll
            for (int j = 0; j < 8; j++) {
                float s = (xs[i] + es[j]) - 2.0f * acc[i][j];
                if (s < rmin[i]) { rmin[i] = s; ridx[i] = kt + nf + j; }
            }
    }
    __syncthreads();
    float* redm = sx;
    int* redi = (int*)se;
    const int c = (wave & 1) * 8 + ln;
    #pragma unroll
    for (int i = 0; i < 8; i++) {
        int r = (wave >> 1) * 64 + lm * 8 + i;
        redm[r * 16 + c] = rmin[i];
        redi[r * 16 + c] = ridx[i];
    }
    __syncthreads();
    if (t < BM) {
        float bst = redm[t * 16];
        int bi = redi[t * 16];
        #pragma unroll
        for (int c2 = 1; c2 < 16; c2++) {
            float v = redm[t * 16 + c2];
            int id = redi[t * 16 + c2];
            if (v < bst || (v == bst && id < bi)) { bst = v; bi = id; }
        }
        pmin[(size_t)(row0 + t) * KSPLIT + blockIdx.y] = bst;
        pidx[(size_t)(row0 + t) * KSPLIT + blockIdx.y] = bi;
    }
}

__global__ void vq_final(const float* __restrict__ E, const float* __restrict__ pmin,
                         const int* __restrict__ pidx, float* __restrict__ out_q,
                         float* __restrict__ out_idx) {
    int row = blockIdx.x;
    int lane = threadIdx.x;
    float bst = pmin[(size_t)row * KSPLIT];
    int bi = pidx[(size_t)row * KSPLIT];
    #pragma unroll
    for (int s = 1; s < KSPLIT; s++) {
        float v = pmin[(size_t)row * KSPLIT + s];
        int id = pidx[(size_t)row * KSPLIT + s];
        if (v < bst || (v == bst && id < bi)) { bst = v; bi = id; }
    }
    if (lane == 0) out_idx[row] = (float)bi;
    float4 v = ((const float4*)(E + (size_t)bi * D))[lane];
    ((float4*)(out_q + (size_t)row * D))[lane] = v;
}

// =======================================================================
extern "C" void kernel_launch(void* const* d_in, const int* in_sizes, int n_in,
                              void* d_out, int out_size, void* d_ws, size_t ws_size,
                              hipStream_t stream) {
    const float* X = (const float*)d_in[0];  // [N, D]
    const float* E = (const float*)d_in[1];  // [K, D]
    float* out_q = (float*)d_out;
    float* out_idx = (float*)d_out + (size_t)N * D;

    // fast-path ws: Xh(8M) Eh(4M) esq(32K) pcand(N*CS*16 = 2M) ~= 14.3MB
    const size_t need = (size_t)12 * 1024 * 1024 + 32768 + (size_t)N * CS * 16;
    if (ws_size >= need) {
        _Float16* Xh = (_Float16*)d_ws;
        _Float16* Eh = Xh + (size_t)N * D;
        float* esq = (float*)(Eh + (size_t)K * D);
        float4* pcand = (float4*)(esq + K);

        const int prep_grid = (N * 32) / 256 + (K * 32) / 256 + (K * 64) / 256;
        vq_prep<<<prep_grid, 256, 0, stream>>>(X, E, Xh, Eh, esq);
        dim3 grid(N / 256, CS);
        vq_mfma<<<grid, 256, 0, stream>>>(Xh, Eh, esq, pcand);
        vq_rescore<<<N / 4, 256, 0, stream>>>(X, E, pcand, out_q, out_idx);
    } else {
        float* esq = (float*)d_ws;
        float* xsq = esq + K;
        float* pmin = xsq + N;
        int* pidx = (int*)(pmin + (size_t)N * KSPLIT);
        vq_rowsq<<<K, 64, 0, stream>>>(E, esq);
        vq_rowsq<<<N, 64, 0, stream>>>(X, xsq);
        dim3 grid(N / BM, KSPLIT);
        vq_main<<<grid, 256, 0, stream>>>(X, E, xsq, esq, pmin, pidx);
        vq_final<<<N, 64, 0, stream>>>(E, pmin, pidx, out_q, out_idx);
    }
}